// Round 1
// baseline (89.509 us; speedup 1.0000x reference)
//
#include <hip/hip_runtime.h>

#define IN_SZ 108
#define NPIX (IN_SZ * IN_SZ)      // 11664 floats per channel
#define NV4  (NPIX / 4)           // 2916 float4 per channel
#define V4_PER_ROW (IN_SZ / 4)    // 27

__device__ __forceinline__ float maskv(float x, float off, float end) {
    // sigmoid(10*(x-off)) - sigmoid(10*(x-end))
    float a = 1.0f / (1.0f + __expf(-10.0f * (x - off)));
    float b = 1.0f / (1.0f + __expf(-10.0f * (x - end)));
    return a - b;
}

__global__ __launch_bounds__(256) void attn_crop_kernel(
    const float* __restrict__ images,
    const float* __restrict__ locs,
    float* __restrict__ out)
{
    __shared__ float s_img[NPIX];                       // 46656 B, one channel
    __shared__ float s_wr0[IN_SZ], s_wr1[IN_SZ];        // row weights (incl. mask)
    __shared__ float s_wc0[IN_SZ], s_wc1[IN_SZ];        // col weights (incl. mask)
    __shared__ int   s_r0[IN_SZ], s_r1[IN_SZ];          // row offsets (pre-mul by 108)
    __shared__ int   s_c0[IN_SZ], s_c1[IN_SZ];          // col indices

    const int img = blockIdx.x;
    const int tid = threadIdx.x;

    // ---- per-image box (all threads compute; scalar broadcast loads) ----
    const float l0 = locs[3 * img + 0];
    const float l1 = locs[3 * img + 1];
    const float l2 = locs[3 * img + 2];
    const float tx = 54.0f + truncf(l0 * 27.0f + 0.5f);
    const float ty = 54.0f + truncf(l1 * 27.0f + 0.5f);
    const float tl = 21.0f + truncf(l2 * 7.0f + 0.5f);
    const float w_off = fmaxf(tx - tl, 0.0f);
    const float h_off = fmaxf(ty - tl, 0.0f);
    const float w_end = fminf(tx + tl, 108.0f);
    const float h_end = fminf(ty + tl, 108.0f);

    // ---- per-row / per-col sampling tables ----
    if (tid < IN_SZ) {
        const float fj = (float)tid;
        // reference order: w_off + (j * (w_end - w_off - 1)) / 107
        float sr = w_off + (fj * (w_end - w_off - 1.0f)) / 107.0f;
        float fl = fminf(fmaxf(floorf(sr), 0.0f), 107.0f);
        int r0 = (int)fl;
        int r1 = min(r0 + 1, 107);
        float fr = sr - (float)r0;
        float m0 = maskv((float)r0, w_off, w_end);
        float m1 = maskv((float)r1, w_off, w_end);
        s_wr0[tid] = (1.0f - fr) * m0;
        s_wr1[tid] = fr * m1;
        s_r0[tid] = r0 * IN_SZ;
        s_r1[tid] = r1 * IN_SZ;
    } else if (tid >= 128 && tid < 128 + IN_SZ) {
        const int k = tid - 128;
        const float fk = (float)k;
        float sc = h_off + (fk * (h_end - h_off - 1.0f)) / 107.0f;
        float fl = fminf(fmaxf(floorf(sc), 0.0f), 107.0f);
        int c0 = (int)fl;
        int c1 = min(c0 + 1, 107);
        float fc = sc - (float)c0;
        float m0 = maskv((float)c0, h_off, h_end);
        float m1 = maskv((float)c1, h_off, h_end);
        s_wc0[k] = (1.0f - fc) * m0;
        s_wc1[k] = fc * m1;
        s_c0[k] = c0;
        s_c1[k] = c1;
    }

    const float* imgbase = images + (size_t)img * (3 * NPIX);
    float*       outbase = out    + (size_t)img * (3 * NPIX);

    for (int ch = 0; ch < 3; ++ch) {
        __syncthreads();   // tables ready (ch=0) / previous compute done (ch>0)
        // ---- stage channel into LDS, coalesced float4 ----
        const float4* src = (const float4*)(imgbase + ch * NPIX);
        float4* s4 = (float4*)s_img;
        for (int i = tid; i < NV4; i += 256) s4[i] = src[i];
        __syncthreads();

        // ---- bilinear gather + masked weights, float4 stores ----
        float4* dst = (float4*)(outbase + ch * NPIX);
        for (int t = tid; t < NV4; t += 256) {
            int j  = t / V4_PER_ROW;
            int k0 = (t - j * V4_PER_ROW) * 4;
            float wr0 = s_wr0[j], wr1 = s_wr1[j];
            int r0o = s_r0[j], r1o = s_r1[j];
            float4 v;
            float* vp = (float*)&v;
#pragma unroll
            for (int q = 0; q < 4; ++q) {
                int k = k0 + q;
                int c0 = s_c0[k], c1 = s_c1[k];
                float a = s_img[r0o + c0] * wr0 + s_img[r1o + c0] * wr1;
                float b = s_img[r0o + c1] * wr0 + s_img[r1o + c1] * wr1;
                vp[q] = a * s_wc0[k] + b * s_wc1[k];
            }
            dst[t] = v;
        }
    }
}

extern "C" void kernel_launch(void* const* d_in, const int* in_sizes, int n_in,
                              void* d_out, int out_size, void* d_ws, size_t ws_size,
                              hipStream_t stream) {
    const float* images = (const float*)d_in[0];
    const float* locs   = (const float*)d_in[1];
    float* out = (float*)d_out;
    const int nimg = in_sizes[1] / 3;   // locs is [nimg, 3]
    attn_crop_kernel<<<dim3(nimg), dim3(256), 0, stream>>>(images, locs, out);
}

// Round 3
// 80.947 us; speedup vs baseline: 1.1058x; 1.1058x over previous
//
#include <hip/hip_runtime.h>

#define IN_SZ 108
#define NPIX (IN_SZ * IN_SZ)      // 11664 floats per channel
#define NV4  (NPIX / 4)           // 2916 float4 per channel
#define V4_PER_ROW (IN_SZ / 4)    // 27

typedef float f32x4 __attribute__((ext_vector_type(4)));

__device__ __forceinline__ float maskv(float x, float off, float end) {
    // sigmoid(10*(x-off)) - sigmoid(10*(x-end))
    float a = 1.0f / (1.0f + __expf(-10.0f * (x - off)));
    float b = 1.0f / (1.0f + __expf(-10.0f * (x - end)));
    return a - b;
}

__global__ __launch_bounds__(256) void attn_crop_kernel(
    const float* __restrict__ images,
    const float* __restrict__ locs,
    float* __restrict__ out)
{
    __shared__ float s_wr0[IN_SZ], s_wr1[IN_SZ];   // row weights (incl. mask)
    __shared__ float s_wc0[IN_SZ], s_wc1[IN_SZ];   // col weights (incl. mask)
    __shared__ int   s_r0[IN_SZ], s_r1[IN_SZ];     // row offsets (pre-mul by 108)
    __shared__ int   s_c0[IN_SZ], s_c1[IN_SZ];     // col indices

    const int blk = blockIdx.x;          // img*3 + ch
    const int img = blk / 3;
    const int tid = threadIdx.x;

    // ---- per-image box (all threads compute; scalar broadcast loads) ----
    const float l0 = locs[3 * img + 0];
    const float l1 = locs[3 * img + 1];
    const float l2 = locs[3 * img + 2];
    const float tx = 54.0f + truncf(l0 * 27.0f + 0.5f);
    const float ty = 54.0f + truncf(l1 * 27.0f + 0.5f);
    const float tl = 21.0f + truncf(l2 * 7.0f + 0.5f);
    const float w_off = fmaxf(tx - tl, 0.0f);
    const float h_off = fmaxf(ty - tl, 0.0f);
    const float w_end = fminf(tx + tl, 108.0f);
    const float h_end = fminf(ty + tl, 108.0f);

    // ---- per-row / per-col sampling tables (3.4 KB LDS total) ----
    if (tid < IN_SZ) {
        const float fj = (float)tid;
        // reference order: w_off + (j * (w_end - w_off - 1)) / 107
        float sr = w_off + (fj * (w_end - w_off - 1.0f)) / 107.0f;
        float fl = fminf(fmaxf(floorf(sr), 0.0f), 107.0f);
        int r0 = (int)fl;
        int r1 = min(r0 + 1, 107);
        float fr = sr - (float)r0;
        s_wr0[tid] = (1.0f - fr) * maskv((float)r0, w_off, w_end);
        s_wr1[tid] = fr * maskv((float)r1, w_off, w_end);
        s_r0[tid] = r0 * IN_SZ;
        s_r1[tid] = r1 * IN_SZ;
    } else if (tid >= 128 && tid < 128 + IN_SZ) {
        const int k = tid - 128;
        const float fk = (float)k;
        float sc = h_off + (fk * (h_end - h_off - 1.0f)) / 107.0f;
        float fl = fminf(fmaxf(floorf(sc), 0.0f), 107.0f);
        int c0 = (int)fl;
        int c1 = min(c0 + 1, 107);
        float fc = sc - (float)c0;
        s_wc0[k] = (1.0f - fc) * maskv((float)c0, h_off, h_end);
        s_wc1[k] = fc * maskv((float)c1, h_off, h_end);
        s_c0[k] = c0;
        s_c1[k] = c1;
    }
    __syncthreads();

    const float* __restrict__ src = images + (size_t)blk * NPIX;
    float*       __restrict__ dst = out    + (size_t)blk * NPIX;

    // ---- bilinear gather straight from global (L1/L2-served) ----
    for (int t = tid; t < NV4; t += 256) {
        int j  = t / V4_PER_ROW;
        int k0 = (t - j * V4_PER_ROW) * 4;
        float wr0 = s_wr0[j], wr1 = s_wr1[j];
        const float* __restrict__ row0 = src + s_r0[j];
        const float* __restrict__ row1 = src + s_r1[j];
        f32x4 v;
#pragma unroll
        for (int q = 0; q < 4; ++q) {
            int k = k0 + q;
            int c0 = s_c0[k], c1 = s_c1[k];
            float a = row0[c0] * wr0 + row1[c0] * wr1;
            float b = row0[c1] * wr0 + row1[c1] * wr1;
            v[q] = a * s_wc0[k] + b * s_wc1[k];
        }
        __builtin_nontemporal_store(v, (f32x4*)(dst + 4 * (size_t)t));
    }
}

extern "C" void kernel_launch(void* const* d_in, const int* in_sizes, int n_in,
                              void* d_out, int out_size, void* d_ws, size_t ws_size,
                              hipStream_t stream) {
    const float* images = (const float*)d_in[0];
    const float* locs   = (const float*)d_in[1];
    float* out = (float*)d_out;
    const int nimg = in_sizes[1] / 3;   // locs is [nimg, 3]
    attn_crop_kernel<<<dim3(nimg * 3), dim3(256), 0, stream>>>(images, locs, out);
}

// Round 4
// 80.627 us; speedup vs baseline: 1.1102x; 1.0040x over previous
//
#include <hip/hip_runtime.h>

#define IN_SZ 108
#define NPIX (IN_SZ * IN_SZ)
#define BUF_STRIDE 112          // dwords per staged source row (109 used)

__device__ __forceinline__ float maskv(float x, float off, float end) {
    // sigmoid(10*(x-off)) - sigmoid(10*(x-end))
    float a = 1.0f / (1.0f + __expf(-10.0f * (x - off)));
    float b = 1.0f / (1.0f + __expf(-10.0f * (x - end)));
    return a - b;
}

__global__ __launch_bounds__(256) void attn_crop_kernel(
    const float* __restrict__ images,
    const float* __restrict__ locs,
    float* __restrict__ out)
{
    // per-wave staged source-row pair; waves never share -> no __syncthreads
    __shared__ float s_buf[4][2][BUF_STRIDE];

    const int blk = blockIdx.x;          // img*3 + ch
    const int img = blk / 3;
    const int tid = threadIdx.x;
    const int w   = tid >> 6;            // wave id (0..3)
    const int l   = tid & 63;            // lane (0..63)

    // ---- per-image box (uniform; compiler scalarizes) ----
    const float l0 = locs[3 * img + 0];
    const float l1 = locs[3 * img + 1];
    const float l2 = locs[3 * img + 2];
    const float tx = 54.0f + truncf(l0 * 27.0f + 0.5f);
    const float ty = 54.0f + truncf(l1 * 27.0f + 0.5f);
    const float tl = 21.0f + truncf(l2 * 7.0f + 0.5f);
    const float w_off = fmaxf(tx - tl, 0.0f);
    const float h_off = fmaxf(ty - tl, 0.0f);
    const float w_end = fminf(tx + tl, 108.0f);
    const float h_end = fminf(ty + tl, 108.0f);

    // ---- per-lane column params, registers only (k = l and k = 64+l) ----
    const float cspan = h_end - h_off - 1.0f;
    // col A: k = l
    float scA  = h_off + ((float)l * cspan) / 107.0f;        // reference eval order
    float flA  = fminf(fmaxf(floorf(scA), 0.0f), 107.0f);
    int   c0A  = (int)flA;
    int   c1A  = min(c0A + 1, 107);
    float fcA  = scA - flA;
    float wc0A = (1.0f - fcA) * maskv((float)c0A, h_off, h_end);
    float wc1A = fcA * maskv((float)c1A, h_off, h_end);
    // col B: k = 64+l (lanes >=44 compute harmlessly, never store)
    int   kB   = min(64 + l, 107);
    float scB  = h_off + ((float)kB * cspan) / 107.0f;
    float flB  = fminf(fmaxf(floorf(scB), 0.0f), 107.0f);
    int   c0B  = (int)flB;
    int   c1B  = min(c0B + 1, 107);
    float fcB  = scB - flB;
    float wc0B = (1.0f - fcB) * maskv((float)c0B, h_off, h_end);
    float wc1B = fcB * maskv((float)c1B, h_off, h_end);
    (void)c1A; (void)c1B;  // gather uses c0+1 with dup@108; weights use clamped c1

    const float* __restrict__ src = images + (size_t)blk * NPIX;
    float*       __restrict__ dst = out    + (size_t)blk * NPIX;
    float* buf0 = &s_buf[w][0][0];
    float* buf1 = &s_buf[w][1][0];
    const float rspan = w_end - w_off - 1.0f;

    for (int j = w; j < IN_SZ; j += 4) {
        // ---- row params (wave-uniform) ----
        float sr  = w_off + ((float)j * rspan) / 107.0f;
        float flr = fminf(fmaxf(floorf(sr), 0.0f), 107.0f);
        int   r0  = (int)flr;
        int   r1  = min(r0 + 1, 107);
        float fr  = sr - flr;
        float wr0 = (1.0f - fr) * maskv((float)r0, w_off, w_end);
        float wr1 = fr * maskv((float)r1, w_off, w_end);
        const float* __restrict__ r0p = src + r0 * IN_SZ;
        const float* __restrict__ r1p = src + r1 * IN_SZ;

        // ---- stage two source rows, coalesced; entry 108 dups 107 ----
        float a0 = r0p[l];
        float b0 = r1p[l];
        float a1 = 0.0f, b1 = 0.0f;
        if (l < 45) {
            int c = min(64 + l, 107);
            a1 = r0p[c];
            b1 = r1p[c];
        }
        buf0[l] = a0;
        buf1[l] = b0;
        if (l < 45) {
            buf0[64 + l] = a1;
            buf1[64 + l] = b1;
        }
        asm volatile("s_waitcnt lgkmcnt(0)" ::: "memory");  // writes visible wave-wide

        // ---- gather pairs from LDS + bilinear ----
        float u00 = buf0[c0A], u01 = buf0[c0A + 1];
        float u10 = buf1[c0A], u11 = buf1[c0A + 1];
        float oA = (u00 * wr0 + u10 * wr1) * wc0A + (u01 * wr0 + u11 * wr1) * wc1A;
        float v00 = buf0[c0B], v01 = buf0[c0B + 1];
        float v10 = buf1[c0B], v11 = buf1[c0B + 1];
        float oB = (v00 * wr0 + v10 * wr1) * wc0B + (v01 * wr0 + v11 * wr1) * wc1B;

        __builtin_nontemporal_store(oA, dst + j * IN_SZ + l);
        if (l < 44)
            __builtin_nontemporal_store(oB, dst + j * IN_SZ + 64 + l);

        asm volatile("s_waitcnt lgkmcnt(0)" ::: "memory");  // reads done before next overwrite
    }
}

extern "C" void kernel_launch(void* const* d_in, const int* in_sizes, int n_in,
                              void* d_out, int out_size, void* d_ws, size_t ws_size,
                              hipStream_t stream) {
    const float* images = (const float*)d_in[0];
    const float* locs   = (const float*)d_in[1];
    float* out = (float*)d_out;
    const int nimg = in_sizes[1] / 3;   // locs is [nimg, 3]
    attn_crop_kernel<<<dim3(nimg * 3), dim3(256), 0, stream>>>(images, locs, out);
}

// Round 5
// 46.260 us; speedup vs baseline: 1.9349x; 1.7429x over previous
//
#include <hip/hip_runtime.h>

#define IN_SZ 108
#define NPIX (IN_SZ * IN_SZ)
#define BUFS 112                 // dword stride of a staged source row (109 used)

typedef float f32x2 __attribute__((ext_vector_type(2)));

__device__ __forceinline__ float maskv(float x, float off, float end) {
    // sigmoid(10*(x-off)) - sigmoid(10*(x-end))
    float a = 1.0f / (1.0f + __expf(-10.0f * (x - off)));
    float b = 1.0f / (1.0f + __expf(-10.0f * (x - end)));
    return a - b;
}

__global__ __launch_bounds__(256) void attn_crop_kernel(
    const float* __restrict__ images,
    const float* __restrict__ locs,
    float* __restrict__ out)
{
    __shared__ float4 s_row[IN_SZ];            // packed: wr0, wr1, r0*108, r1*108 (bitcast)
    __shared__ float  s_buf[4][2][2][BUFS];    // [wave][parity][r0/r1][col] double-buffered

    const int blk = blockIdx.x;          // img*3 + ch
    const int img = blk / 3;
    const int tid = threadIdx.x;
    const int w   = tid >> 6;            // wave id
    const int l   = tid & 63;            // lane

    // ---- per-image box ----
    const float l0 = locs[3 * img + 0];
    const float l1 = locs[3 * img + 1];
    const float l2 = locs[3 * img + 2];
    const float tx = 54.0f + truncf(l0 * 27.0f + 0.5f);
    const float ty = 54.0f + truncf(l1 * 27.0f + 0.5f);
    const float tl = 21.0f + truncf(l2 * 7.0f + 0.5f);
    const float w_off = fmaxf(tx - tl, 0.0f);
    const float h_off = fmaxf(ty - tl, 0.0f);
    const float w_end = fminf(tx + tl, 108.0f);
    const float h_end = fminf(ty + tl, 108.0f);

    // ---- row table: built ONCE per block (one expf pass, threads 0..107) ----
    if (tid < IN_SZ) {
        float fj  = (float)tid;
        float sr  = w_off + (fj * (w_end - w_off - 1.0f)) / 107.0f;   // reference order
        float flr = fminf(fmaxf(floorf(sr), 0.0f), 107.0f);
        int   r0  = (int)flr;
        int   r1  = min(r0 + 1, 107);
        float fr  = sr - flr;
        float4 p;
        p.x = (1.0f - fr) * maskv((float)r0, w_off, w_end);
        p.y = fr * maskv((float)r1, w_off, w_end);
        p.z = __int_as_float(r0 * IN_SZ);
        p.w = __int_as_float(r1 * IN_SZ);
        s_row[tid] = p;
    }

    // ---- col params: two adjacent columns (2l, 2l+1) per lane, registers ----
    const float cspan = h_end - h_off - 1.0f;
    const int kA = min(2 * l, 107), kB = min(2 * l + 1, 107);
    float scA  = h_off + ((float)kA * cspan) / 107.0f;
    float flA  = fminf(fmaxf(floorf(scA), 0.0f), 107.0f);
    int   c0A  = (int)flA;
    float fcA  = scA - flA;
    float wc0A = (1.0f - fcA) * maskv((float)c0A, h_off, h_end);
    float wc1A = fcA * maskv((float)min(c0A + 1, 107), h_off, h_end);
    float scB  = h_off + ((float)kB * cspan) / 107.0f;
    float flB  = fminf(fmaxf(floorf(scB), 0.0f), 107.0f);
    int   c0B  = (int)flB;
    float fcB  = scB - flB;
    float wc0B = (1.0f - fcB) * maskv((float)c0B, h_off, h_end);
    float wc1B = fcB * maskv((float)min(c0B + 1, 107), h_off, h_end);

    __syncthreads();

    const float* __restrict__ src = images + (size_t)blk * NPIX;
    float*       __restrict__ dst = out    + (size_t)blk * NPIX;
    const bool act = (l < 54);           // 54 lanes cover 108 cols (2 each)

    // ---- prologue: params + prefetch for first row ----
    float4 p = s_row[w];
    f32x2 a = {0.f, 0.f}, b = {0.f, 0.f};
    if (act) {
        a = *(const f32x2*)(src + __float_as_int(p.z) + 2 * l);
        b = *(const f32x2*)(src + __float_as_int(p.w) + 2 * l);
    }

    int j = w;
    for (int i = 0; i < 27; ++i) {
        float* b0 = &s_buf[w][i & 1][0][0];
        float* b1 = &s_buf[w][i & 1][1][0];
        // stage prefetched row pair (compiler inserts vmcnt wait on a,b)
        if (act) {
            *(f32x2*)(b0 + 2 * l) = a;
            *(f32x2*)(b1 + 2 * l) = b;
            if (l == 53) { b0[IN_SZ] = a.y; b1[IN_SZ] = b.y; }  // dup col 107 -> 108
        }
        // next row's params + prefetch (into the other LDS buffer next iter)
        float4 pn = p;
        f32x2 an = {0.f, 0.f}, bn = {0.f, 0.f};
        if (i < 26) {
            pn = s_row[j + 4];
            if (act) {
                an = *(const f32x2*)(src + __float_as_int(pn.z) + 2 * l);
                bn = *(const f32x2*)(src + __float_as_int(pn.w) + 2 * l);
            }
        }
        asm volatile("s_waitcnt lgkmcnt(0)" ::: "memory");   // staging visible wave-wide
        const float wr0 = p.x, wr1 = p.y;
        float u00 = b0[c0A], u01 = b0[c0A + 1];
        float u10 = b1[c0A], u11 = b1[c0A + 1];
        float v00 = b0[c0B], v01 = b0[c0B + 1];
        float v10 = b1[c0B], v11 = b1[c0B + 1];
        f32x2 o;
        o.x = (u00 * wr0 + u10 * wr1) * wc0A + (u01 * wr0 + u11 * wr1) * wc1A;
        o.y = (v00 * wr0 + v10 * wr1) * wc0B + (v01 * wr0 + v11 * wr1) * wc1B;
        if (act) *(f32x2*)(dst + j * IN_SZ + 2 * l) = o;
        p = pn; a = an; b = bn; j += 4;
    }
}

extern "C" void kernel_launch(void* const* d_in, const int* in_sizes, int n_in,
                              void* d_out, int out_size, void* d_ws, size_t ws_size,
                              hipStream_t stream) {
    const float* images = (const float*)d_in[0];
    const float* locs   = (const float*)d_in[1];
    float* out = (float*)d_out;
    const int nimg = in_sizes[1] / 3;   // locs is [nimg, 3]
    attn_crop_kernel<<<dim3(nimg * 3), dim3(256), 0, stream>>>(images, locs, out);
}

// Round 6
// 39.002 us; speedup vs baseline: 2.2950x; 1.1861x over previous
//
#include <hip/hip_runtime.h>

#define IN_SZ 108
#define NPIX (IN_SZ * IN_SZ)

typedef float f32x2 __attribute__((ext_vector_type(2)));

__device__ __forceinline__ float maskv(float x, float off, float end) {
    // sigmoid(10*(x-off)) - sigmoid(10*(x-end))
    float a = 1.0f / (1.0f + __expf(-10.0f * (x - off)));
    float b = 1.0f / (1.0f + __expf(-10.0f * (x - end)));
    return a - b;
}

__global__ __launch_bounds__(256) void attn_crop_kernel(
    const float* __restrict__ images,
    const float* __restrict__ locs,
    float* __restrict__ out)
{
    __shared__ float4 s_row[IN_SZ];   // wr0, wr1, r0*108 (bits), r1*108 (bits)

    const int blk = blockIdx.x;       // img*3 + ch
    const int img = blk / 3;
    const int tid = threadIdx.x;
    const int w   = tid >> 6;         // wave id (0..3)
    const int l   = tid & 63;         // lane

    // ---- per-image box ----
    const float l0 = locs[3 * img + 0];
    const float l1 = locs[3 * img + 1];
    const float l2 = locs[3 * img + 2];
    const float tx = 54.0f + truncf(l0 * 27.0f + 0.5f);
    const float ty = 54.0f + truncf(l1 * 27.0f + 0.5f);
    const float tl = 21.0f + truncf(l2 * 7.0f + 0.5f);
    const float w_off = fmaxf(tx - tl, 0.0f);
    const float h_off = fmaxf(ty - tl, 0.0f);
    const float w_end = fminf(tx + tl, 108.0f);
    const float h_end = fminf(ty + tl, 108.0f);

    // ---- row table: built once (one expf pass, threads 0..107) ----
    if (tid < IN_SZ) {
        float fj  = (float)tid;
        float sr  = w_off + (fj * (w_end - w_off - 1.0f)) / 107.0f;  // reference order
        float flr = fminf(fmaxf(floorf(sr), 0.0f), 107.0f);
        int   r0  = (int)flr;
        int   r1  = min(r0 + 1, 107);
        float fr  = sr - flr;
        float4 p;
        p.x = (1.0f - fr) * maskv((float)r0, w_off, w_end);
        p.y = fr * maskv((float)r1, w_off, w_end);
        p.z = __int_as_float(r0 * IN_SZ);
        p.w = __int_as_float(r1 * IN_SZ);
        s_row[tid] = p;
    }

    // ---- per-lane column params (cols 2l, 2l+1), loop-invariant ----
    const float cspan = h_end - h_off - 1.0f;
    const int kA = min(2 * l, 107), kB = min(2 * l + 1, 107);
    float scA  = h_off + ((float)kA * cspan) / 107.0f;
    float flA  = fminf(fmaxf(floorf(scA), 0.0f), 107.0f);
    int   c0A  = (int)flA;
    float fcA  = scA - flA;
    float wc0A = (1.0f - fcA) * maskv((float)c0A, h_off, h_end);
    float wc1A = fcA * maskv((float)min(c0A + 1, 107), h_off, h_end);
    float scB  = h_off + ((float)kB * cspan) / 107.0f;
    float flB  = fminf(fmaxf(floorf(scB), 0.0f), 107.0f);
    int   c0B  = (int)flB;
    float fcB  = scB - flB;
    float wc0B = (1.0f - fcB) * maskv((float)c0B, h_off, h_end);
    float wc1B = fcB * maskv((float)min(c0B + 1, 107), h_off, h_end);

    // q0..q3 after shfl = interpolated cols {2*li0, 2*li0+1, 2*li0+2, 2*li0+3}
    // col c0A = index 'par' in that window; c0B starts at par+d (d = c0B-c0A in {0,1})
    const int li0 = c0A >> 1;
    const int par = c0A & 1;
    const int d   = c0B - c0A;
    const int sy  = par + d;
    const float Wx0 = par ? 0.0f  : wc0A;
    const float Wx1 = par ? wc0A  : wc1A;
    const float Wx2 = par ? wc1A  : 0.0f;
    const float Wy0 = (sy == 0) ? wc0B : 0.0f;
    const float Wy1 = (sy == 0) ? wc1B : ((sy == 1) ? wc0B : 0.0f);
    const float Wy2 = (sy == 1) ? wc1B : ((sy == 2) ? wc0B : 0.0f);
    const float Wy3 = (sy == 2) ? wc1B : 0.0f;

    __syncthreads();

    const float* __restrict__ src = images + (size_t)blk * NPIX;
    float*       __restrict__ dst = out    + (size_t)blk * NPIX;
    const int colLoad = min(2 * l, 106);     // keep all lanes in-bounds

    // ---- prologue: params + loads for iterations 0 and 1 ----
    float4 p0 = s_row[w];
    float4 p1 = s_row[w + 4];
    f32x2 A0 = *(const f32x2*)(src + __float_as_int(p0.z) + colLoad);
    f32x2 B0 = *(const f32x2*)(src + __float_as_int(p0.w) + colLoad);
    f32x2 A1 = *(const f32x2*)(src + __float_as_int(p1.z) + colLoad);
    f32x2 B1 = *(const f32x2*)(src + __float_as_int(p1.w) + colLoad);

    int j = w;
    for (int i = 0; i < 27; ++i) {
        // prefetch iteration i+2 (distance-2: ~2 iterations of latency slack)
        float4 p2 = p1;
        f32x2 A2 = A1, B2 = B1;
        if (i < 25) {
            p2 = s_row[j + 8];
            A2 = *(const f32x2*)(src + __float_as_int(p2.z) + colLoad);
            B2 = *(const f32x2*)(src + __float_as_int(p2.w) + colLoad);
        }
        // fold rows first (wr0, wr1 wave-uniform), then cross-lane gather
        const float wr0 = p0.x, wr1 = p0.y;
        f32x2 M;
        M.x = A0.x * wr0 + B0.x * wr1;
        M.y = A0.y * wr0 + B0.y * wr1;
        float q0 = __shfl(M.x, li0);
        float q1 = __shfl(M.y, li0);
        float q2 = __shfl(M.x, li0 + 1);
        float q3 = __shfl(M.y, li0 + 1);
        f32x2 o;
        o.x = q0 * Wx0 + q1 * Wx1 + q2 * Wx2;
        o.y = q0 * Wy0 + q1 * Wy1 + q2 * Wy2 + q3 * Wy3;
        if (l < 54) *(f32x2*)(dst + j * IN_SZ + 2 * l) = o;
        p0 = p1; A0 = A1; B0 = B1;
        p1 = p2; A1 = A2; B1 = B2;
        j += 4;
    }
}

extern "C" void kernel_launch(void* const* d_in, const int* in_sizes, int n_in,
                              void* d_out, int out_size, void* d_ws, size_t ws_size,
                              hipStream_t stream) {
    const float* images = (const float*)d_in[0];
    const float* locs   = (const float*)d_in[1];
    float* out = (float*)d_out;
    const int nimg = in_sizes[1] / 3;   // locs is [nimg, 3]
    attn_crop_kernel<<<dim3(nimg * 3), dim3(256), 0, stream>>>(images, locs, out);
}